// Round 3
// baseline (2269.363 us; speedup 1.0000x reference)
//
#include <hip/hip_runtime.h>

typedef unsigned short u16;
typedef unsigned int   u32;

#define DI __device__ __forceinline__

DI float b2f(u16 u){ union{u32 i; float f;} x; x.i = ((u32)u)<<16; return x.f; }
DI u16 f2bf(float f){ union{float f; u32 i;} x; x.f=f; u32 r = x.i + 0x7FFFu + ((x.i>>16)&1u); return (u16)(r>>16); }
DI float sigf(float x){ return 1.0f/(1.0f + __expf(-x)); }
DI float tanh_(float x){ return 1.0f - 2.0f/(__expf(2.0f*x)+1.0f); }
DI float dot4(float4 a, float4 b){ return a.x*b.x + a.y*b.y + a.z*b.z + a.w*b.w; }

// ---------------- conv1 (k=7,pad3) + BN1 + ReLU + maxpool2 ----------------
// x: [128][2048][8] f32  -> out: [128][128][1024] bf16  (layout [b][co][t'])
__global__ __launch_bounds__(256) void k_conv1(
    const float* __restrict__ x, const float* __restrict__ w,
    const float* __restrict__ cb, const float* __restrict__ bg, const float* __restrict__ bb,
    const float* __restrict__ bm, const float* __restrict__ bv, u16* __restrict__ out)
{
  __shared__ __align__(16) float xs[262*8];
  __shared__ __align__(16) float wl[128*7*8];   // [co][k][ci]
  __shared__ float As[128], Ss[128];
  const int tid = threadIdx.x;
  const int tc  = blockIdx.x;       // 8 chunks of 128 pooled positions
  const int b   = blockIdx.y;
  const int tau0 = tc*256;
  for(int f = tid; f < 262*8; f += 256){
    int tt = f >> 3;
    int ci = f & 7;
    int xg = tau0 - 3 + tt;
    float val = 0.f;
    if(xg >= 0 && xg < 2048) val = x[(b*2048 + xg)*8 + ci];
    xs[f] = val;
  }
  for(int d = tid; d < 128*7*8; d += 256){
    int co = d / 56; int r = d - co*56; int k = r >> 3; int ci = r & 7;
    wl[d] = w[(co*8 + ci)*7 + k];
  }
  if(tid < 128){
    float a = bg[tid] * rsqrtf(bv[tid] + 1e-5f);
    As[tid] = a;
    Ss[tid] = (cb[tid] - bm[tid])*a + bb[tid];
  }
  __syncthreads();
  const float4* xs4 = (const float4*)xs;
  const float4* wl4 = (const float4*)wl;
  for(int i = 0; i < 64; i++){
    int idx = i*256 + tid;
    int co = idx >> 7, p = idx & 127;
    float4 xa[8], xb[8];
    #pragma unroll
    for(int d=0; d<8; d++){ xa[d] = xs4[(2*p + d)*2]; xb[d] = xs4[(2*p + d)*2 + 1]; }
    float a0 = 0.f, a1 = 0.f;
    #pragma unroll
    for(int k=0;k<7;k++){
      float4 wa = wl4[(co*7+k)*2], wb = wl4[(co*7+k)*2+1];
      a0 += dot4(xa[k],   wa) + dot4(xb[k],   wb);
      a1 += dot4(xa[k+1], wa) + dot4(xb[k+1], wb);
    }
    float Ac = As[co], Sc = Ss[co];
    float y = fmaxf(fmaxf(a0*Ac+Sc, a1*Ac+Sc), 0.f);
    out[((b*128 + co)<<10) + tc*128 + p] = f2bf(y);
  }
}

// ---------------- conv2 (k=5,pad2) + BN2 + ReLU + maxpool2 ----------------
// in: [128][128][1024] bf16 -> seq: [512][128][256] bf16 (layout [t'][b][co])
__global__ __launch_bounds__(256) void k_conv2(
    const u16* __restrict__ cin, const float* __restrict__ w,
    const float* __restrict__ cb, const float* __restrict__ bg, const float* __restrict__ bb,
    const float* __restrict__ bm, const float* __restrict__ bv, u16* __restrict__ seq)
{
  __shared__ __align__(16) float xs[16*132];
  __shared__ __align__(16) float wl[64*16*8];   // [c][ci][k(pad8)]
  __shared__ float As[64], Ss[64];
  const int tid = threadIdx.x;
  const int tc  = blockIdx.x;    // 0..7  (64 pooled t' per chunk)
  const int cog = blockIdx.y;    // 0..3  (64 co per group)
  const int b   = blockIdx.z;
  const int co0 = cog*64;
  const int tau0 = tc*128;
  if(tid < 64){
    int co = co0 + tid;
    float a = bg[co] * rsqrtf(bv[co] + 1e-5f);
    As[tid] = a; Ss[tid] = (cb[co] - bm[co])*a + bb[co];
  }
  const int q  = tid & 15;       // t' group of 4
  const int cg = tid >> 4;       // co group of 4
  float acc[4][4][2];
  #pragma unroll
  for(int c=0;c<4;c++)
    #pragma unroll
    for(int tl=0;tl<4;tl++){ acc[c][tl][0]=0.f; acc[c][tl][1]=0.f; }
  for(int ci0 = 0; ci0 < 128; ci0 += 16){
    __syncthreads();
    for(int f = tid; f < 16*132; f += 256){
      int ci = f / 132, tt = f - ci*132;
      int tg = tau0 + tt - 2;
      float val = 0.f;
      if(tg >= 0 && tg < 1024) val = b2f(cin[((b*128 + ci0+ci)<<10) + tg]);
      xs[f] = val;
    }
    for(int f = tid; f < 64*16*5; f += 256){
      int c = f / 80; int r = f - c*80; int ci = r/5; int k = r - ci*5;
      wl[(c*16+ci)*8 + k] = w[((co0+c)*128 + ci0+ci)*5 + k];
    }
    __syncthreads();
    #pragma unroll 4
    for(int ci = 0; ci < 16; ci++){
      const float4* xr = (const float4*)&xs[ci*132 + 8*q];
      float4 x0 = xr[0], x1 = xr[1], x2 = xr[2];
      float xv[12];
      xv[0]=x0.x; xv[1]=x0.y; xv[2]=x0.z; xv[3]=x0.w;
      xv[4]=x1.x; xv[5]=x1.y; xv[6]=x1.z; xv[7]=x1.w;
      xv[8]=x2.x; xv[9]=x2.y; xv[10]=x2.z; xv[11]=x2.w;
      #pragma unroll
      for(int c=0;c<4;c++){
        const float* wp = &wl[((cg*4+c)*16 + ci)*8];
        float w0=wp[0], w1=wp[1], w2=wp[2], w3=wp[3], w4=wp[4];
        #pragma unroll
        for(int tl=0; tl<4; tl++){
          acc[c][tl][0] += xv[2*tl+0]*w0 + xv[2*tl+1]*w1 + xv[2*tl+2]*w2 + xv[2*tl+3]*w3 + xv[2*tl+4]*w4;
          acc[c][tl][1] += xv[2*tl+1]*w0 + xv[2*tl+2]*w1 + xv[2*tl+3]*w2 + xv[2*tl+4]*w3 + xv[2*tl+5]*w4;
        }
      }
    }
  }
  #pragma unroll
  for(int c=0;c<4;c++){
    float Ac = As[cg*4+c], Sc = Ss[cg*4+c];
    #pragma unroll
    for(int tl=0;tl<4;tl++){
      float y0 = acc[c][tl][0]*Ac + Sc;
      float y1 = acc[c][tl][1]*Ac + Sc;
      float y  = fmaxf(fmaxf(y0, y1), 0.f);
      int tp = tc*64 + q*4 + tl;
      seq[(tp*128 + b)*256 + co0 + cg*4 + c] = f2bf(y);
    }
  }
}

// ---------------- xp = LN(seq @ wih.T + bih)  (per direction) ----------------
// seq: [65536 rows][256] bf16 ; wih: [384][256] f32 ; out xp: [rows][384] bf16
__global__ __launch_bounds__(512) void k_xp(
    const u16* __restrict__ seq,
    const float* __restrict__ fw, const float* __restrict__ fbi, const float* __restrict__ fg, const float* __restrict__ fb,
    const float* __restrict__ bw, const float* __restrict__ bbi, const float* __restrict__ bg_, const float* __restrict__ bb_,
    u16* __restrict__ xpf, u16* __restrict__ xpb)
{
  __shared__ __align__(16) float sT[32*36];     // [k][r] pitch 36
  __shared__ __align__(16) float wT[32*386];    // [k][j] pitch 386
  const float *W, *BI, *LG, *LB; u16* out;
  if(blockIdx.y == 0){ W=fw; BI=fbi; LG=fg;  LB=fb;  out=xpf; }
  else               { W=bw; BI=bbi; LG=bg_; LB=bb_; out=xpb; }
  const int tid = threadIdx.x;
  const int row0 = blockIdx.x * 32;
  const int jg = tid & 63, rg = tid >> 6;       // wave rg owns rows rg*4..+3
  const int j0 = jg*6;
  float bi6[6], g6[6], b6[6];
  #pragma unroll
  for(int e=0;e<6;e++){ bi6[e]=BI[j0+e]; g6[e]=LG[j0+e]; b6[e]=LB[j0+e]; }
  float acc[4][6];
  #pragma unroll
  for(int r=0;r<4;r++)
    #pragma unroll
    for(int e=0;e<6;e++) acc[r][e]=0.f;
  for(int k0=0;k0<256;k0+=32){
    __syncthreads();
    {
      int r = tid >> 4; int kk = (tid & 15)*2;
      u32 pv = *(const u32*)&seq[(row0 + r)*256 + k0 + kk];
      sT[kk*36 + r]     = b2f((u16)(pv & 0xffffu));
      sT[(kk+1)*36 + r] = b2f((u16)(pv >> 16));
    }
    #pragma unroll
    for(int rep=0; rep<24; rep++){
      int flat = rep*512 + tid;                 // 0..12287 = 384*32
      int j = flat >> 5; int kk = flat & 31;
      wT[kk*386 + j] = W[j*256 + k0 + kk];
    }
    __syncthreads();
    #pragma unroll 8
    for(int kk=0;kk<32;kk++){
      float4 s4 = *(const float4*)&sT[kk*36 + rg*4];   // wave-broadcast
      const float* wp = &wT[kk*386 + j0];
      #pragma unroll
      for(int e=0;e<6;e++){
        float wv = wp[e];
        acc[0][e] += s4.x*wv;
        acc[1][e] += s4.y*wv;
        acc[2][e] += s4.z*wv;
        acc[3][e] += s4.w*wv;
      }
    }
  }
  #pragma unroll
  for(int r=0;r<4;r++){
    float s=0.f, ss=0.f;
    #pragma unroll
    for(int e=0;e<6;e++){
      float u = acc[r][e] + bi6[e];
      acc[r][e] = u;
      s += u; ss += u*u;
    }
    #pragma unroll
    for(int msk=32; msk; msk>>=1){ s += __shfl_xor(s,msk); ss += __shfl_xor(ss,msk); }
    float mean = s * (1.f/384.f);
    float var  = fmaxf(ss * (1.f/384.f) - mean*mean, 0.f);
    float rs = rsqrtf(var + 1e-5f);
    int row = row0 + rg*4 + r;
    u32 o01 = (u32)f2bf((acc[r][0]-mean)*rs*g6[0] + b6[0]) | ((u32)f2bf((acc[r][1]-mean)*rs*g6[1] + b6[1]) << 16);
    u32 o23 = (u32)f2bf((acc[r][2]-mean)*rs*g6[2] + b6[2]) | ((u32)f2bf((acc[r][3]-mean)*rs*g6[3] + b6[3]) << 16);
    u32 o45 = (u32)f2bf((acc[r][4]-mean)*rs*g6[4] + b6[4]) | ((u32)f2bf((acc[r][5]-mean)*rs*g6[5] + b6[5]) << 16);
    u32* op = (u32*)(out + row*384 + j0);
    op[0]=o01; op[1]=o23; op[2]=o45;
  }
}

// ---------------- LayerNorm-LSTM scan (one block per (batch,dir)) ----------------
__global__ __launch_bounds__(384) void k_lstm(
    const u16* __restrict__ xpf, const u16* __restrict__ xpb,
    const float* __restrict__ fwhh, const float* __restrict__ fbhh, const float* __restrict__ fgh, const float* __restrict__ fbh2,
    const float* __restrict__ fgho, const float* __restrict__ fbho,
    const float* __restrict__ bwhh, const float* __restrict__ bbhh, const float* __restrict__ bgh, const float* __restrict__ bbh2,
    const float* __restrict__ bgho, const float* __restrict__ bbho,
    u16* __restrict__ hcat)
{
  __shared__ float4 hx4[24];
  __shared__ float gbuf[384];
  __shared__ float red[16];
  const int b   = blockIdx.x;
  const int dir = blockIdx.y;
  const u16* xp;
  const float *whh, *bh, *gh, *bh2, *gho, *bho;
  if(dir == 0){ xp=xpf; whh=fwhh; bh=fbhh; gh=fgh; bh2=fbh2; gho=fgho; bho=fbho; }
  else        { xp=xpb; whh=bwhh; bh=bbhh; gh=bgh; bh2=bbh2; gho=bgho; bho=bbho; }
  const int j = threadIdx.x;
  const int wid = j >> 6;
  float wr[96];                         // whh row j in registers
  {
    const float4* wp4 = (const float4*)(whh + j*96);
    #pragma unroll
    for(int kk=0; kk<24; kk++){
      float4 v = wp4[kk];
      wr[4*kk]=v.x; wr[4*kk+1]=v.y; wr[4*kk+2]=v.z; wr[4*kk+3]=v.w;
    }
  }
  const float bh_j = bh[j], gh_j = gh[j], bh2_j = bh2[j];
  float gho_j = 0.f, bho_j = 0.f, cx = 0.f;
  if(j < 96){ gho_j = gho[j]; bho_j = bho[j]; }
  float* hx = (float*)hx4;
  if(j < 96) hx[j] = 0.f;
  __syncthreads();
  for(int t=0; t<512; t++){
    const int ts = dir ? (511 - t) : t;
    const float xt = b2f(xp[(ts*128 + b)*384 + j]);
    float a0=0.f,a1=0.f,a2=0.f,a3=0.f;
    #pragma unroll
    for(int kk=0; kk<24; kk++){
      float4 h4 = hx4[kk];              // broadcast read
      a0 += h4.x * wr[4*kk];
      a1 += h4.y * wr[4*kk+1];
      a2 += h4.z * wr[4*kk+2];
      a3 += h4.w * wr[4*kk+3];
    }
    const float u = (a0+a1)+(a2+a3) + bh_j;
    float s = u, ss = u*u;
    #pragma unroll
    for(int msk=32; msk; msk>>=1){ s += __shfl_xor(s,msk); ss += __shfl_xor(ss,msk); }
    if((j & 63) == 0){ red[wid*2] = s; red[wid*2+1] = ss; }
    __syncthreads();
    float S=0.f, SS=0.f;
    #pragma unroll
    for(int wv=0; wv<6; wv++){ S += red[wv*2]; SS += red[wv*2+1]; }
    const float mean = S*(1.f/384.f);
    const float var  = fmaxf(SS*(1.f/384.f) - mean*mean, 0.f);
    const float rs   = rsqrtf(var + 1e-5f);
    const float gate = xt + (u - mean)*rs*gh_j + bh2_j;
    gbuf[j] = gate;
    __syncthreads();
    float cy = 0.f, go_ = 0.f;
    if(j < 128){
      if(j < 96){
        float gi = gbuf[j], gf = gbuf[j+96], gg = gbuf[j+192];
        go_ = gbuf[j+288];
        cy = sigf(gf)*cx + sigf(gi)*tanh_(gg);
        cx = cy;
      }
      float s2 = cy, ss2 = cy*cy;
      #pragma unroll
      for(int msk=32; msk; msk>>=1){ s2 += __shfl_xor(s2,msk); ss2 += __shfl_xor(ss2,msk); }
      if((j & 63) == 0){ red[12 + wid*2] = s2; red[13 + wid*2] = ss2; }
    }
    __syncthreads();
    if(j < 96){
      const float S2 = red[12]+red[14], SS2 = red[13]+red[15];
      const float m2  = S2*(1.f/96.f);
      const float v2  = fmaxf(SS2*(1.f/96.f) - m2*m2, 0.f);
      const float rs2 = rsqrtf(v2 + 1e-5f);
      const float lnho = (cy - m2)*rs2*gho_j + bho_j;
      const float hy = sigf(go_)*tanh_(lnho);
      hx[j] = hy;
      hcat[(ts*128 + b)*192 + dir*96 + j] = f2bf(hy);
    }
    __syncthreads();
  }
}

// ---------------- attention + fc1/BN3/ReLU + fc2 (one block per batch) ----------------
__global__ __launch_bounds__(256) void k_head(
    const u16* __restrict__ hcat, const float* __restrict__ aw,
    const float* __restrict__ f1w, const float* __restrict__ f1b,
    const float* __restrict__ g3, const float* __restrict__ b3, const float* __restrict__ m3, const float* __restrict__ v3,
    const float* __restrict__ fc2w, const float* __restrict__ fc2bias,
    float* __restrict__ out)
{
  __shared__ float p[512];
  __shared__ float red[8];
  __shared__ __align__(16) float ctx[192];
  __shared__ float h2[256];
  __shared__ float awl[192];
  const int b = blockIdx.x;
  const int tid = threadIdx.x;
  if(tid < 192) awl[tid] = aw[tid];
  __syncthreads();
  float sc0 = 0.f, sc1 = 0.f;
  #pragma unroll
  for(int i=0;i<2;i++){
    int t = i*256 + tid;
    const uint4* hp = (const uint4*)(hcat + (t*128 + b)*192);
    float acc = 0.f;
    #pragma unroll 6
    for(int qq=0;qq<24;qq++){
      uint4 pv = hp[qq];
      acc += b2f((u16)(pv.x&0xffffu))*awl[qq*8+0] + b2f((u16)(pv.x>>16))*awl[qq*8+1]
           + b2f((u16)(pv.y&0xffffu))*awl[qq*8+2] + b2f((u16)(pv.y>>16))*awl[qq*8+3]
           + b2f((u16)(pv.z&0xffffu))*awl[qq*8+4] + b2f((u16)(pv.z>>16))*awl[qq*8+5]
           + b2f((u16)(pv.w&0xffffu))*awl[qq*8+6] + b2f((u16)(pv.w>>16))*awl[qq*8+7];
    }
    if(i==0) sc0 = acc; else sc1 = acc;
  }
  float mx = fmaxf(sc0, sc1);
  for(int msk=32; msk; msk>>=1) mx = fmaxf(mx, __shfl_xor(mx,msk));
  if((tid&63)==0) red[tid>>6] = mx;
  __syncthreads();
  mx = fmaxf(fmaxf(red[0],red[1]), fmaxf(red[2],red[3]));
  float e0 = __expf(sc0-mx), e1 = __expf(sc1-mx);
  float sm = e0 + e1;
  for(int msk=32; msk; msk>>=1) sm += __shfl_xor(sm,msk);
  if((tid&63)==0) red[4 + (tid>>6)] = sm;
  __syncthreads();
  const float inv = 1.f/(red[4]+red[5]+red[6]+red[7]);
  p[tid] = e0*inv; p[tid+256] = e1*inv;
  __syncthreads();
  if(tid < 192){
    float acc = 0.f;
    for(int t=0;t<512;t++){
      acc += p[t] * b2f(hcat[(t*128 + b)*192 + tid]);
    }
    ctx[tid] = acc;
  }
  __syncthreads();
  {
    const float4* cv = (const float4*)ctx;
    const float4* wp = (const float4*)(f1w + tid*192);
    float acc = 0.f;
    #pragma unroll 8
    for(int qq=0;qq<48;qq++){
      acc += dot4(wp[qq], cv[qq]);
    }
    acc += f1b[tid];
    float a = g3[tid] * rsqrtf(v3[tid] + 1e-5f);
    float y = (acc - m3[tid])*a + b3[tid];
    h2[tid] = fmaxf(y, 0.f);
  }
  __syncthreads();
  if(tid < 6){
    float acc = fc2bias[tid];
    for(int k=0;k<256;k++) acc += h2[k]*fc2w[tid*256 + k];
    out[b*6 + tid] = acc;
  }
}

extern "C" void kernel_launch(void* const* d_in, const int* in_sizes, int n_in,
                              void* d_out, int out_size, void* d_ws, size_t ws_size,
                              hipStream_t stream)
{
  (void)in_sizes; (void)n_in; (void)out_size; (void)ws_size;
  const float* X      = (const float*)d_in[0];
  const float* c1w    = (const float*)d_in[1];
  const float* c1b    = (const float*)d_in[2];
  const float* bn1g   = (const float*)d_in[3];
  const float* bn1b   = (const float*)d_in[4];
  const float* bn1m   = (const float*)d_in[5];
  const float* bn1v   = (const float*)d_in[6];
  const float* c2w    = (const float*)d_in[7];
  const float* c2b    = (const float*)d_in[8];
  const float* bn2g   = (const float*)d_in[9];
  const float* bn2b   = (const float*)d_in[10];
  const float* bn2m   = (const float*)d_in[11];
  const float* bn2v   = (const float*)d_in[12];
  const float* fwih   = (const float*)d_in[13];
  const float* fbih   = (const float*)d_in[14];
  const float* fwhh   = (const float*)d_in[15];
  const float* fbhh   = (const float*)d_in[16];
  const float* flnihg = (const float*)d_in[17];
  const float* flnihb = (const float*)d_in[18];
  const float* flnhhg = (const float*)d_in[19];
  const float* flnhhb = (const float*)d_in[20];
  const float* flnhog = (const float*)d_in[21];
  const float* flnhob = (const float*)d_in[22];
  const float* bwih   = (const float*)d_in[23];
  const float* bbih   = (const float*)d_in[24];
  const float* bwhh   = (const float*)d_in[25];
  const float* bbhh   = (const float*)d_in[26];
  const float* blnihg = (const float*)d_in[27];
  const float* blnihb = (const float*)d_in[28];
  const float* blnhhg = (const float*)d_in[29];
  const float* blnhhb = (const float*)d_in[30];
  const float* blnhog = (const float*)d_in[31];
  const float* blnhob = (const float*)d_in[32];
  const float* attnw  = (const float*)d_in[33];
  const float* fc1w   = (const float*)d_in[34];
  const float* fc1b   = (const float*)d_in[35];
  const float* bn3g   = (const float*)d_in[36];
  const float* bn3b   = (const float*)d_in[37];
  const float* bn3m   = (const float*)d_in[38];
  const float* bn3v   = (const float*)d_in[39];
  const float* fc2w   = (const float*)d_in[40];
  const float* fc2b_  = (const float*)d_in[41];

  // Workspace layout (peak 128 MiB), liveness-based overlays:
  //   seq  @   0 .. 32M   (conv2 out; dead after k_xp)
  //   xpf  @  32M .. 80M
  //   xpb  @  80M ..128M  (overlays dead c1o tail region timing-wise: c1o dead after conv2)
  //   c1o  @  96M ..128M  (conv1 out; dead after conv2)   [xpb written after c1o is dead]
  //   hcat @   0 .. 24M   (lstm out; overlays dead seq)
  char* ws = (char*)d_ws;
  const size_t MB = 1048576;
  u16* seq  = (u16*)(ws);
  u16* xpf  = (u16*)(ws + 32*MB);
  u16* xpb  = (u16*)(ws + 80*MB);
  u16* c1o  = (u16*)(ws + 96*MB);
  u16* hcat = (u16*)(ws);

  k_conv1<<<dim3(8,128),  256, 0, stream>>>(X,   c1w, c1b, bn1g, bn1b, bn1m, bn1v, c1o);
  k_conv2<<<dim3(8,4,128),256, 0, stream>>>(c1o, c2w, c2b, bn2g, bn2b, bn2m, bn2v, seq);
  k_xp  <<<dim3(2048,2),  512, 0, stream>>>(seq, fwih, fbih, flnihg, flnihb,
                                                 bwih, bbih, blnihg, blnihb, xpf, xpb);
  k_lstm<<<dim3(128,2),   384, 0, stream>>>(xpf, xpb,
      fwhh, fbhh, flnhhg, flnhhb, flnhog, flnhob,
      bwhh, bbhh, blnhhg, blnhhb, blnhog, blnhob, hcat);
  k_head<<<dim3(128),     256, 0, stream>>>(hcat, attnw, fc1w, fc1b,
      bn3g, bn3b, bn3m, bn3v, fc2w, fc2b_, (float*)d_out);
}